// Round 1
// baseline (211.975 us; speedup 1.0000x reference)
//
#include <hip/hip_runtime.h>
#include <math.h>

// LCAHeavyParentLoss: scalar = mean over [B,C] of BCE(outputs,targets)
// + greedy-path parent cascade. B=2048, C=11110 (branching=10, depth=4).
//
// Reduction: result = ( Σ_{B,C} [softplus(x) - x*t] + Σ_rows cascade ) / (B*C)
// cascade per row (path = greedy argmax walk, parent(path[l]) == path[l-1]):
//   add_3 = [t3==0]*sp(x3); add_2 = [t2==0]*(sp(x2)+add_3); add_1 = [t1==0]*(sp(x1)+add_2)
//   extra = add_1 + add_2 + add_3

#define BRANCH 10
#define DEPTH  4
#define C_COLS 11110   // sum_{l=0..3} 10^(l+1)

__device__ __forceinline__ float softplus_f(float x) {
    // stable logaddexp(0,x) = max(x,0) + log1p(exp(-|x|))
    return fmaxf(x, 0.0f) + log1pf(expf(-fabsf(x)));
}

__global__ void zero_out_kernel(float* out) { out[0] = 0.0f; }

__global__ __launch_bounds__(256) void bce_sum_kernel(
    const float4* __restrict__ x4, const float4* __restrict__ t4,
    float* __restrict__ out, int n4, float inv_scale)
{
    int tid    = blockIdx.x * blockDim.x + threadIdx.x;
    int stride = gridDim.x * blockDim.x;
    float s = 0.0f;
    for (int i = tid; i < n4; i += stride) {
        float4 xv = x4[i];
        float4 tv = t4[i];
        s += softplus_f(xv.x) - xv.x * tv.x;
        s += softplus_f(xv.y) - xv.y * tv.y;
        s += softplus_f(xv.z) - xv.z * tv.z;
        s += softplus_f(xv.w) - xv.w * tv.w;
    }
    // wave64 reduction
    #pragma unroll
    for (int off = 32; off > 0; off >>= 1)
        s += __shfl_down(s, off, 64);
    __shared__ float wsum[4];
    int lane = threadIdx.x & 63;
    int wid  = threadIdx.x >> 6;
    if (lane == 0) wsum[wid] = s;
    __syncthreads();
    if (threadIdx.x == 0) {
        float bs = wsum[0] + wsum[1] + wsum[2] + wsum[3];
        atomicAdd(out, bs * inv_scale);
    }
}

__global__ __launch_bounds__(256) void path_cascade_kernel(
    const float* __restrict__ x, const float* __restrict__ t,
    float* __restrict__ out, int n_rows, float inv_scale)
{
    int row = blockIdx.x * blockDim.x + threadIdx.x;
    if (row >= n_rows) return;
    const float* xr = x + (size_t)row * C_COLS;
    const float* tr = t + (size_t)row * C_COLS;

    int   e[DEPTH];
    float xv[DEPTH];
    int node = 0;
    #pragma unroll
    for (int l = 0; l < DEPTH; ++l) {
        int base = node * BRANCH;
        float best = xr[base];
        int   bi   = 0;
        #pragma unroll
        for (int c = 1; c < BRANCH; ++c) {
            float v = xr[base + c];
            if (v > best) { best = v; bi = c; }   // first-max tie-break, matches argmax
        }
        e[l]  = base + bi;
        xv[l] = best;
        node  = e[l] + 1;
    }

    float total = 0.0f, carry = 0.0f;
    #pragma unroll
    for (int l = DEPTH - 1; l >= 1; --l) {
        float tl   = tr[e[l]];
        float addl = (tl == 0.0f) ? (softplus_f(xv[l]) + carry) : 0.0f;
        total += addl;
        carry  = addl;
    }
    if (total != 0.0f) atomicAdd(out, total * inv_scale);
}

extern "C" void kernel_launch(void* const* d_in, const int* in_sizes, int n_in,
                              void* d_out, int out_size, void* d_ws, size_t ws_size,
                              hipStream_t stream) {
    const float* outputs = (const float*)d_in[0];
    const float* targets = (const float*)d_in[1];
    float* out = (float*)d_out;

    const int total = in_sizes[0];          // B * C
    const int B     = total / C_COLS;       // 2048
    const int n4    = total / 4;            // divisible: C even, B = 2^11
    const float inv = 1.0f / (float)total;

    zero_out_kernel<<<1, 1, 0, stream>>>(out);

    bce_sum_kernel<<<2048, 256, 0, stream>>>(
        (const float4*)outputs, (const float4*)targets, out, n4, inv);

    path_cascade_kernel<<<(B + 255) / 256, 256, 0, stream>>>(
        outputs, targets, out, B, inv);
}

// Round 2
// 200.604 us; speedup vs baseline: 1.0567x; 1.0567x over previous
//
#include <hip/hip_runtime.h>
#include <math.h>

// LCAHeavyParentLoss: scalar = mean over [B,C] of BCE-with-logits(outputs,targets)
// + greedy-path parent cascade. B=2048, C=11110 (branching=10, depth=4).
//
// result = ( SUM_{B,C} [softplus(x) - x*t] + SUM_rows cascade ) / (B*C)
// cascade per row (greedy argmax walk; parent(path[l]) == path[l-1]):
//   add_3=[t3==0]*sp(x3); add_2=[t2==0]*(sp(x2)+add_3); add_1=[t1==0]*(sp(x1)+add_2)
//   extra = add_1+add_2+add_3
//
// R2: libm expf/log1pf were ~100 lane-ops/elem (VALUBusy 78%, issue-bound).
// Replaced with v_exp_f32/v_log_f32 base-2 identity (~8 ops/elem).
// 2-kernel structure: partials in d_ws (no zeroing kernel, no atomics);
// path cascade folded into first 2048 threads of the main kernel.

#define BRANCH 10
#define DEPTH  4
#define C_COLS 11110
#define NBLK   2048
#define NTHR   256

__device__ __forceinline__ float softplus_fast(float x) {
    // softplus(x) = max(x,0) + ln2 * log2(1 + exp2(-|x|*log2e))
    float ax = __builtin_fabsf(x);
    float p  = __builtin_amdgcn_exp2f(-1.44269504f * ax);   // v_exp_f32
    float l  = __builtin_amdgcn_logf(1.0f + p);             // v_log_f32 (log2)
    return __builtin_fmaxf(x, 0.0f) + 0.69314718f * l;
}

__global__ __launch_bounds__(NTHR) void bce_path_kernel(
    const float* __restrict__ x, const float* __restrict__ t,
    float* __restrict__ partials, int n4, int n_rows)
{
    const float4* __restrict__ x4 = (const float4*)x;
    const float4* __restrict__ t4 = (const float4*)t;

    int tid    = blockIdx.x * blockDim.x + threadIdx.x;
    int stride = gridDim.x * blockDim.x;

    float s0 = 0.0f, s1 = 0.0f, s2 = 0.0f, s3 = 0.0f;

    // --- path cascade: one row per global thread (only first n_rows threads) ---
    if (tid < n_rows) {
        const float* xr = x + (size_t)tid * C_COLS;
        const float* tr = t + (size_t)tid * C_COLS;
        int   e[DEPTH];
        float xv[DEPTH];
        int node = 0;
        #pragma unroll
        for (int l = 0; l < DEPTH; ++l) {
            int base = node * BRANCH;
            float best = xr[base];
            int   bi   = 0;
            #pragma unroll
            for (int c = 1; c < BRANCH; ++c) {
                float v = xr[base + c];
                if (v > best) { best = v; bi = c; }   // first-max, matches jnp.argmax
            }
            e[l]  = base + bi;
            xv[l] = best;
            node  = e[l] + 1;
        }
        float carry = 0.0f;
        #pragma unroll
        for (int l = DEPTH - 1; l >= 1; --l) {
            float addl = (tr[e[l]] == 0.0f) ? (softplus_fast(xv[l]) + carry) : 0.0f;
            s0   += addl;
            carry = addl;
        }
    }

    // --- main BCE sum, float4 grid-stride ---
    for (int i = tid; i < n4; i += stride) {
        float4 xv = x4[i];
        float4 tv = t4[i];
        s0 += softplus_fast(xv.x) - xv.x * tv.x;
        s1 += softplus_fast(xv.y) - xv.y * tv.y;
        s2 += softplus_fast(xv.z) - xv.z * tv.z;
        s3 += softplus_fast(xv.w) - xv.w * tv.w;
    }
    float s = (s0 + s1) + (s2 + s3);

    // wave64 reduce
    #pragma unroll
    for (int off = 32; off > 0; off >>= 1)
        s += __shfl_down(s, off, 64);
    __shared__ float wsum[NTHR / 64];
    int lane = threadIdx.x & 63;
    int wid  = threadIdx.x >> 6;
    if (lane == 0) wsum[wid] = s;
    __syncthreads();
    if (threadIdx.x == 0)
        partials[blockIdx.x] = (wsum[0] + wsum[1]) + (wsum[2] + wsum[3]);
}

__global__ __launch_bounds__(NTHR) void final_reduce_kernel(
    const float* __restrict__ partials, float* __restrict__ out, float inv_scale)
{
    const float4* p4 = (const float4*)partials;   // NBLK/4 = 512 float4
    float s = 0.0f;
    for (int i = threadIdx.x; i < NBLK / 4; i += NTHR) {
        float4 v = p4[i];
        s += (v.x + v.y) + (v.z + v.w);
    }
    #pragma unroll
    for (int off = 32; off > 0; off >>= 1)
        s += __shfl_down(s, off, 64);
    __shared__ float wsum[NTHR / 64];
    int lane = threadIdx.x & 63;
    int wid  = threadIdx.x >> 6;
    if (lane == 0) wsum[wid] = s;
    __syncthreads();
    if (threadIdx.x == 0)
        out[0] = ((wsum[0] + wsum[1]) + (wsum[2] + wsum[3])) * inv_scale;
}

extern "C" void kernel_launch(void* const* d_in, const int* in_sizes, int n_in,
                              void* d_out, int out_size, void* d_ws, size_t ws_size,
                              hipStream_t stream) {
    const float* outputs = (const float*)d_in[0];
    const float* targets = (const float*)d_in[1];
    float* out      = (float*)d_out;
    float* partials = (float*)d_ws;               // NBLK floats

    const int total = in_sizes[0];                // B * C = 22,753,280
    const int B     = total / C_COLS;             // 2048
    const int n4    = total / 4;
    const float inv = 1.0f / (float)total;

    bce_path_kernel<<<NBLK, NTHR, 0, stream>>>(outputs, targets, partials, n4, B);
    final_reduce_kernel<<<1, NTHR, 0, stream>>>(partials, out, inv);
}